// Round 4
// baseline (456.950 us; speedup 1.0000x reference)
//
#include <hip/hip_runtime.h>

#define N_NODES 8192
#define DIM 128

typedef short bf16x8 __attribute__((ext_vector_type(8)));
typedef unsigned short u16x4 __attribute__((ext_vector_type(4)));
typedef float f32x4 __attribute__((ext_vector_type(4)));

__device__ __forceinline__ unsigned short f2bf_rne(float x) {
    unsigned int u = __builtin_bit_cast(unsigned int, x);
    u += 0x7fffu + ((u >> 16) & 1u);   // round-to-nearest-even
    return (unsigned short)(u >> 16);
}
__device__ __forceinline__ float bf2f(unsigned short h) {
    unsigned int u = ((unsigned int)h) << 16;
    return __builtin_bit_cast(float, u);
}

// ---------------- K1: fused rowsum + A -> bf16 fragment-pack ------------
// Block = 16 rows. Streams A coalesced (2KB bursts/row/chunk), computes
// rowsums, converts to bf16, and writes Abp in MFMA A-fragment order:
//   Abp[rb16][kb][lane][j] = bf16(A[rb16*16 + (lane&15)][kb*32 + (lane>>4)*8 + j])
// so k_spmm's A-loads are contiguous 16B/lane wave-loads.
__global__ __launch_bounds__(256) void k_prep(const float* __restrict__ A,
                                              unsigned short* __restrict__ Abp,
                                              float* __restrict__ d) {
    __shared__ unsigned short tile[16 * 512];   // 16KB, XOR-swizzled bf16 chunk
    __shared__ float rs[2][8][128];             // 8KB rowsum partials
    const int t = threadIdx.x;
    const int lane = t & 63, wv = t >> 6;
    const int l15 = lane & 15, quad = lane >> 4;
    const int rb16 = blockIdx.x;
    const float* Ag0 = A + (size_t)rb16 * 16 * N_NODES;
    const int h = t >> 7;              // 0/1: which row parity this thread loads
    const int c4 = (t & 127) << 2;     // f32 col within chunk
    float rsum[8] = {};

    // prologue: chunk 0 loads
    f32x4 pre[8];
#pragma unroll
    for (int i = 0; i < 8; ++i)
        pre[i] = *(const f32x4*)(Ag0 + (size_t)(h + 2 * i) * N_NODES + c4);

    for (int chunk = 0; chunk < 16; ++chunk) {
        f32x4 curv[8];
#pragma unroll
        for (int i = 0; i < 8; ++i) curv[i] = pre[i];
        if (chunk < 15) {
            const float* Ag = Ag0 + (chunk + 1) * 512;
#pragma unroll
            for (int i = 0; i < 8; ++i)
                pre[i] = *(const f32x4*)(Ag + (size_t)(h + 2 * i) * N_NODES + c4);
        }
        __syncthreads();               // prior pack-phase reads of tile done
#pragma unroll
        for (int i = 0; i < 8; ++i) {
            int r = h + 2 * i;
            f32x4 v = curv[i];
            rsum[i] += (v[0] + v[1]) + (v[2] + v[3]);
            int byte = (r * 1024 + c4 * 2) ^ ((r & 7) << 4);
            u16x4 pk = { f2bf_rne(v[0]), f2bf_rne(v[1]), f2bf_rne(v[2]), f2bf_rne(v[3]) };
            *(u16x4*)((char*)tile + byte) = pk;
        }
        __syncthreads();
        // pack phase: wave wv handles 4 k-blocks of this chunk
#pragma unroll
        for (int u = 0; u < 4; ++u) {
            int kk = wv * 4 + u;
            int abyte = (l15 * 1024 + (kk * 32 + quad * 8) * 2) ^ ((l15 & 7) << 4);
            bf16x8 frag = *(const bf16x8*)((const char*)tile + abyte);
            int kbg = chunk * 16 + kk;
            *(bf16x8*)(Abp + ((size_t)(rb16 * 256 + kbg) * 64 + lane) * 8) = frag;
        }
    }

    // rowsum reduction: row r partials live in rsum[r>>1] of threads with h==(r&1)
#pragma unroll
    for (int i = 0; i < 8; ++i) rs[h][i][t & 127] = rsum[i];
    __syncthreads();
    if (t < 16) {
        const float* p = rs[t & 1][t >> 1];
        float s = 0.f;
        for (int j = 0; j < 128; ++j) s += p[j];
        d[rb16 * 16 + t] = rsqrtf(s + 1.0f);   // +1 for the identity diagonal
    }
}

// ---------------- K2: Zp = pack_B( bf16( diag(d) * X * W^T ) ) ----------
// B-fragment order: Zp[kb][c16][lane][j] = Z[kb*32 + (lane>>4)*8 + j][c16*16 + (lane&15)]
__global__ __launch_bounds__(256) void k_zgemm(const float* __restrict__ X,
                                               const float* __restrict__ W,
                                               const float* __restrict__ d,
                                               unsigned short* __restrict__ Zp) {
    __shared__ float Xs[64][129];
    __shared__ float Ws[64][129];
    int rb = blockIdx.x >> 1;
    int cb = blockIdx.x & 1;
    int t = threadIdx.x;
    const float4* Xg = (const float4*)(X + (size_t)rb * 64 * DIM);
    const float4* Wg = (const float4*)(W + (size_t)cb * 64 * DIM);
#pragma unroll
    for (int i = 0; i < 8; ++i) {
        int f = t + i * 256;
        int r = f >> 5;
        int c = (f & 31) << 2;
        float4 v = Xg[f];
        Xs[r][c] = v.x; Xs[r][c + 1] = v.y; Xs[r][c + 2] = v.z; Xs[r][c + 3] = v.w;
        float4 w = Wg[f];
        Ws[r][c] = w.x; Ws[r][c + 1] = w.y; Ws[r][c + 2] = w.z; Ws[r][c + 3] = w.w;
    }
    __syncthreads();
    int tx = t & 15, ty = t >> 4;
    float acc[4][4] = {};
    for (int k = 0; k < DIM; ++k) {
        float xr[4], wr[4];
#pragma unroll
        for (int i = 0; i < 4; ++i) xr[i] = Xs[ty * 4 + i][k];
#pragma unroll
        for (int j = 0; j < 4; ++j) wr[j] = Ws[tx * 4 + j][k];
#pragma unroll
        for (int i = 0; i < 4; ++i)
#pragma unroll
            for (int j = 0; j < 4; ++j)
                acc[i][j] += xr[i] * wr[j];
    }
#pragma unroll
    for (int i = 0; i < 4; ++i) {
        int row = rb * 64 + ty * 4 + i;        // node index (k-dim of spmm)
        float dv = d[row];
        int kb = row >> 5, jj = row & 7;
        int lrow = ((row >> 3) & 3) * 16;
#pragma unroll
        for (int j = 0; j < 4; ++j) {
            int col = cb * 64 + tx * 4 + j;    // feature
            int lanep = lrow + (col & 15);
            Zp[((size_t)(kb * 8 + (col >> 4)) * 64 + lanep) * 8 + jj] =
                f2bf_rne(dv * acc[i][j]);
        }
    }
}

// ---------------- K3: out = diag(d) * ((A+I) @ Z) + b -------------------
// 32 rows x 128 cols per block (256 blocks, 1024 thr, 16 waves = 4/SIMD).
// Wave = (row-half, K-eighth). Halves Zp L2 traffic vs 16-row tiles
// (640 MB total) and the rh-pair waves read identical Zp streams -> L1.
// Cross-wave K-reduction done row-half-sequential through 67.6 KB LDS
// (stride 33 words => 2 lanes/bank, free).
__global__ __launch_bounds__(1024) void k_spmm(const unsigned short* __restrict__ Abp,
                                               const unsigned short* __restrict__ Zp,
                                               const float* __restrict__ d,
                                               const float* __restrict__ bias,
                                               float* __restrict__ out) {
    __shared__ float red[8][64][33];           // 67.6 KB
    const int t = threadIdx.x;
    const int lane = t & 63;
    const int wv = t >> 6;                     // 0..15
    const int rh = wv >> 3;                    // row-half within 32-row tile
    const int kq = wv & 7;                     // K-eighth
    const int l15 = lane & 15, quad = lane >> 4;
    const int rb16 = blockIdx.x * 2 + rh;

    const unsigned short* Ab = Abp + ((size_t)rb16 * 256 * 64 + lane) * 8;
    const unsigned short* Zb = Zp + (size_t)lane * 8;

    f32x4 acc[8];
#pragma unroll
    for (int c = 0; c < 8; ++c) acc[c] = (f32x4){0.f, 0.f, 0.f, 0.f};

#pragma unroll 2
    for (int kb = kq * 32; kb < kq * 32 + 32; ++kb) {
        bf16x8 af = *(const bf16x8*)(Ab + (size_t)kb * 512);
        const unsigned short* zk = Zb + (size_t)kb * 4096;
#pragma unroll
        for (int c = 0; c < 8; ++c) {
            bf16x8 b = *(const bf16x8*)(zk + c * 512);
            acc[c] = __builtin_amdgcn_mfma_f32_16x16x32_bf16(af, b, acc[c], 0, 0, 0);
        }
    }

    // ---- row-half-sequential cross-wave reduction + epilogue
    for (int ph = 0; ph < 2; ++ph) {
        if (rh == ph) {
#pragma unroll
            for (int c = 0; c < 8; ++c)
#pragma unroll
                for (int r = 0; r < 4; ++r)
                    red[kq][lane][c * 4 + r] = acc[c][r];
        }
        __syncthreads();
        {
            // 16 combos (8 col-groups x 2 row-pairs) over 16 waves
            int c = wv & 7;
            int rpair = wv >> 3;
            int col = c * 16 + l15;
            float bcol = bias[col];
#pragma unroll
            for (int rr = 0; rr < 2; ++rr) {
                int r = rpair * 2 + rr;
                float s = 0.f;
#pragma unroll
                for (int k8 = 0; k8 < 8; ++k8) s += red[k8][lane][c * 4 + r];
                int row = blockIdx.x * 32 + ph * 16 + quad * 4 + r;
                // identity term Z[row][col] gathered from packed Zp
                int kbr = row >> 5, jj = row & 7;
                int lanep = ((row >> 3) & 3) * 16 + l15;
                float zid = bf2f(Zp[((size_t)(kbr * 8 + c) * 64 + lanep) * 8 + jj]);
                out[(size_t)row * DIM + col] = d[row] * (s + zid) + bcol;
            }
        }
        __syncthreads();   // phase-0 reads done before phase-1 overwrites
    }
}

extern "C" void kernel_launch(void* const* d_in, const int* in_sizes, int n_in,
                              void* d_out, int out_size, void* d_ws, size_t ws_size,
                              hipStream_t stream) {
    const float* X = (const float*)d_in[0];
    const float* A = (const float*)d_in[1];
    const float* W = (const float*)d_in[2];
    const float* b = (const float*)d_in[3];
    float* out = (float*)d_out;

    char* ws = (char*)d_ws;
    float* dinv = (float*)ws;                               // 32 KB
    unsigned short* Zp = (unsigned short*)(ws + 32768);     // 2 MB  packed Z
    unsigned short* Abp = (unsigned short*)(ws + 32768 + (2u << 20)); // 128 MB packed A

    k_prep<<<512, 256, 0, stream>>>(A, Abp, dinv);
    k_zgemm<<<256, 256, 0, stream>>>(X, W, dinv, Zp);
    k_spmm<<<256, 1024, 0, stream>>>(Abp, Zp, dinv, b, out);
}